// Round 13
// baseline (1585.923 us; speedup 1.0000x reference)
//
#include <hip/hip_runtime.h>
#include <hip/hip_bf16.h>
#include <math.h>

#define B    128
#define CIN  256
#define HIN  8
#define WIN_ 32
#define RH   16
#define RW   64
#define HID  256
#define NC   163
#define T    32
#define L    256
#define CENC 296

typedef __attribute__((ext_vector_type(8))) short short8;
typedef __attribute__((ext_vector_type(8))) unsigned short u16x8;
typedef __attribute__((ext_vector_type(4))) float f32x4;
typedef unsigned long long u64;

// padded f32 mirror addressing: group of 8 floats stored in 12-float slot (48B, 16B-aligned)
#define PH(k) ((((k) >> 3) * 12) + ((k) & 7))
// LDS tile row stride (shorts): 44 -> 88B rows, 16 consecutive rows hit 16 distinct banks
#define TS 44

__device__ __forceinline__ float bf2f(unsigned short u) {
    unsigned int x = ((unsigned int)u) << 16;
    return __uint_as_float(x);
}
__device__ __forceinline__ unsigned short f2bf(float f) {
    unsigned int x = __float_as_uint(f);
    unsigned int r = (x + 0x7FFFu + ((x >> 16) & 1u)) >> 16;
    return (unsigned short)r;
}
__device__ __forceinline__ float fast_tanh(float x) {
    float e = __expf(2.f * x);
    return 1.f - 2.f * __builtin_amdgcn_rcpf(e + 1.f);
}
__device__ __forceinline__ float fast_sigm(float x) {
    return __builtin_amdgcn_rcpf(1.f + __expf(-x));
}
__device__ __forceinline__ float wave_red_max(float v) {
    #pragma unroll
    for (int o = 32; o > 0; o >>= 1) v = fmaxf(v, __shfl_down(v, o, 64));
    return v;
}
__device__ __forceinline__ float wave_red_sum(float v) {
    #pragma unroll
    for (int o = 32; o > 0; o >>= 1) v += __shfl_down(v, o, 64);
    return v;
}
__device__ __forceinline__ float half_red_sum(float v) {
    #pragma unroll
    for (int o = 16; o > 0; o >>= 1) v += __shfl_down(v, o, 64);
    return v;
}

// ---------------- bilinear upsample fused with transpose → Xt[b][y][x][ci] bf16 ----------------
__global__ void __launch_bounds__(256) k_upsxt(const float* __restrict__ x,
                                               unsigned short* __restrict__ Xt) {
    __shared__ __align__(16) float sf[64 * 2 * 32];
    const int y = blockIdx.x;
    const int b = blockIdx.y;
    const int tid = threadIdx.x;
    float sy = 0.5f * y - 0.25f;
    int yq0 = (y - 1) >> 1;
    float wy = sy - (float)yq0;
    int y0c = min(max(yq0, 0), HIN - 1);
    int y1c = min(max(yq0 + 1, 0), HIN - 1);
    const int xo = tid & 63;
    const int cj = tid >> 6;
    float sx = 0.5f * xo - 0.25f;
    int xq0 = (xo - 1) >> 1;
    float wx = sx - (float)xq0;
    int x0c = min(max(xq0, 0), WIN_ - 1);
    int x1c = min(max(xq0 + 1, 0), WIN_ - 1);
    for (int cc = 0; cc < 4; cc++) {
        __syncthreads();
        #pragma unroll
        for (int i = 0; i < 4; i++) {
            int idx = tid * 4 + i;
            int c = idx >> 4;
            int rowh = (idx >> 3) & 1;
            int part = idx & 7;
            int ysrc = rowh ? y1c : y0c;
            float4 v = *reinterpret_cast<const float4*>(
                x + ((size_t)(b * CIN + cc * 64 + c) * HIN + ysrc) * WIN_ + part * 4);
            *reinterpret_cast<float4*>(sf + ((c * 2 + rowh) * 32 + part * 4)) = v;
        }
        __syncthreads();
        unsigned short ov[16];
        #pragma unroll
        for (int j = 0; j < 16; j++) {
            int c = cj * 16 + j;
            const float* r0 = sf + (c * 2 + 0) * 32;
            const float* r1 = sf + (c * 2 + 1) * 32;
            float v = (1.f - wy) * ((1.f - wx) * r0[x0c] + wx * r0[x1c])
                    +        wy  * ((1.f - wx) * r1[x0c] + wx * r1[x1c]);
            ov[j] = f2bf(v);
        }
        unsigned short* dst = Xt + ((size_t)((b * 16 + y) * 64 + xo)) * 256 + cc * 64 + cj * 16;
        *reinterpret_cast<u16x8*>(dst)     = *reinterpret_cast<u16x8*>(ov);
        *reinterpret_cast<u16x8*>(dst + 8) = *reinterpret_cast<u16x8*>(ov + 8);
    }
}

// ---------------- weight transform: Wt[s][co][ci] bf16 ----------------
__global__ void k_wt(const float* __restrict__ conv_w, unsigned short* __restrict__ Wt) {
    int e = blockIdx.x * 256 + threadIdx.x;
    int ci = e & 255;
    int co = (e >> 8) & 255;
    int s  = e >> 16;
    Wt[(size_t)(s * 256 + co) * 256 + ci] = f2bf(conv_w[(size_t)(co * 256 + ci) * 9 + s]);
}

// ---------------- conv3x3 MFMA implicit GEMM + fused bias/ReLU/pool → enc_bf ----------------
// LDS tiles use row stride TS=44 shorts (88B): 16-row ds_read_b128 groups land on 16
// distinct banks (2 lanes/bank for the wave = free), vs stride 40's 4-way conflicts.
__global__ void __launch_bounds__(256) k_convmm(const unsigned short* __restrict__ Xt,
        const unsigned short* __restrict__ Wt, const float* __restrict__ conv_b,
        unsigned short* __restrict__ enc_bf) {
    __shared__ __align__(16) char smem[34048];
    unsigned short* A_s = (unsigned short*)smem;
    unsigned short* B_s = A_s + 128 * TS;
    float* pool = (float*)smem;
    const int mt = blockIdx.x;
    const int n0 = blockIdx.y * 128;
    const int b = mt >> 3;
    const int y0 = (mt & 7) * 2;
    const int tid = threadIdx.x;
    const int wave = tid >> 6, lane = tid & 63;
    const int mq = (wave & 1) * 64, nq = (wave >> 1) * 64;
    const int lm = lane & 15, lq = lane >> 4;
    f32x4 acc[4][4];
    #pragma unroll
    for (int mi = 0; mi < 4; mi++)
        #pragma unroll
        for (int ni = 0; ni < 4; ni++)
            #pragma unroll
            for (int r = 0; r < 4; r++) acc[mi][ni][r] = 0.f;

    for (int s9 = 0; s9 < 9; s9++) {
        const int ky = s9 / 3, kx = s9 % 3;
        const unsigned short* Wb = Wt + (size_t)s9 * 256 * 256;
        for (int kc = 0; kc < 256; kc += 32) {
            __syncthreads();
            #pragma unroll
            for (int it = 0; it < 2; it++) {
                int s2 = tid + it * 256;
                int pix = s2 >> 2, q4 = s2 & 3;
                int yy = y0 + (pix >> 6) + ky - 1;
                int xx = (pix & 63) + kx - 1;
                u16x8 va = {0, 0, 0, 0, 0, 0, 0, 0};
                if ((unsigned)yy < 16u && (unsigned)xx < 64u)
                    va = *reinterpret_cast<const u16x8*>(
                        Xt + ((size_t)((b * 16 + yy) * 64 + xx)) * 256 + kc + q4 * 8);
                *reinterpret_cast<u16x8*>(A_s + pix * TS + q4 * 8) = va;
                u16x8 vb = *reinterpret_cast<const u16x8*>(
                    Wb + (size_t)(n0 + pix) * 256 + kc + q4 * 8);
                *reinterpret_cast<u16x8*>(B_s + pix * TS + q4 * 8) = vb;
            }
            __syncthreads();
            short8 af[4], bfr[4];
            #pragma unroll
            for (int mi = 0; mi < 4; mi++)
                af[mi] = *reinterpret_cast<const short8*>(A_s + (mq + mi * 16 + lm) * TS + lq * 8);
            #pragma unroll
            for (int ni = 0; ni < 4; ni++)
                bfr[ni] = *reinterpret_cast<const short8*>(B_s + (nq + ni * 16 + lm) * TS + lq * 8);
            #pragma unroll
            for (int mi = 0; mi < 4; mi++)
                #pragma unroll
                for (int ni = 0; ni < 4; ni++)
                    acc[mi][ni] = __builtin_amdgcn_mfma_f32_16x16x32_bf16(
                        af[mi], bfr[ni], acc[mi][ni], 0, 0, 0);
        }
    }
    __syncthreads();
    #pragma unroll
    for (int mi = 0; mi < 4; mi++) {
        int px0 = mi * 8 + lq * 2;
        #pragma unroll
        for (int ni = 0; ni < 4; ni++) {
            int nl = nq + ni * 16 + lm;
            float pa = fmaxf(acc[mi][ni][0], acc[mi][ni][1]);
            float pb = fmaxf(acc[mi][ni][2], acc[mi][ni][3]);
            pool[((wave & 1) * 32 + px0) * 132 + nl] = pa;
            pool[((wave & 1) * 32 + px0 + 1) * 132 + nl] = pb;
        }
    }
    __syncthreads();
    {
        int base = tid * 16;
        int px = base >> 7;
        int nb = base & 127;
        unsigned short ov[16];
        #pragma unroll
        for (int i = 0; i < 16; i++) {
            int n = nb + i;
            float v = fmaxf(pool[px * 132 + n], pool[(32 + px) * 132 + n]) + conv_b[n0 + n];
            ov[i] = f2bf(fmaxf(v, 0.f));
        }
        unsigned short* dst = enc_bf + ((size_t)b * L + (mt & 7) * 32 + px) * CENC + n0 + nb;
        *reinterpret_cast<u16x8*>(dst)     = *reinterpret_cast<u16x8*>(ov);
        *reinterpret_cast<u16x8*>(dst + 8) = *reinterpret_cast<u16x8*>(ov + 8);
    }
}

// ---------------- positional channels (bf16) + pos2t[40][256] bf16 ----------------
__global__ void k_encpos(const float* __restrict__ x_emb, const float* __restrict__ y_emb,
                         unsigned short* __restrict__ enc_bf, unsigned short* __restrict__ pos2t) {
    int b = blockIdx.x, l = threadIdx.x;
    int yl = l >> 5, xl = l & 31;
    unsigned short* e = enc_bf + (size_t)(b * L + l) * CENC + 256;
    #pragma unroll
    for (int c = 0; c < 32; c++) e[c] = f2bf(x_emb[xl * 32 + c]);
    #pragma unroll
    for (int c = 0; c < 8; c++) e[32 + c] = f2bf(y_emb[yl * 8 + c]);
    if (b == 0) {
        #pragma unroll
        for (int c = 0; c < 32; c++) pos2t[c * 256 + l] = f2bf(x_emb[xl * 32 + c]);
        #pragma unroll
        for (int c = 0; c < 8; c++) pos2t[(32 + c) * 256 + l] = f2bf(y_emb[yl * 8 + c]);
    }
}

// ---------------- enc_t[b][c][l] bf16 ----------------
__global__ void __launch_bounds__(256) k_enct(const unsigned short* __restrict__ enc_bf,
                                              unsigned short* __restrict__ enc_t) {
    __shared__ unsigned short s[64 * 264];
    const int c0 = blockIdx.x * 64;
    const int b = blockIdx.y;
    const int tid = threadIdx.x;
    #pragma unroll
    for (int j = 0; j < 8; j++) {
        u16x8 u = *reinterpret_cast<const u16x8*>(
            enc_bf + ((size_t)b * L + tid) * CENC + c0 + j * 8);
        #pragma unroll
        for (int k = 0; k < 8; k++) s[(j * 8 + k) * 264 + tid] = u[k];
    }
    __syncthreads();
    {
        int c = tid >> 2, lp = tid & 3;
        const unsigned short* row = s + c * 264 + lp * 64;
        unsigned short* dst = enc_t + ((size_t)b * 256 + c0 + c) * L + lp * 64;
        #pragma unroll
        for (int i = 0; i < 8; i++)
            *reinterpret_cast<u16x8*>(dst + i * 8) =
                *reinterpret_cast<const u16x8*>(row + i * 8);
    }
}

// ---------------- E[v][h] fp32 ----------------
__global__ void __launch_bounds__(256) k_etab(const float* __restrict__ emb_dec,
                                              const float* __restrict__ word_w,
                                              const float* __restrict__ word_b,
                                              float* __restrict__ E) {
    __shared__ float er[NC];
    int row = blockIdx.x, tid = threadIdx.x;
    for (int k = tid; k < NC; k += 256) er[k] = emb_dec[(size_t)row * NC + k];
    __syncthreads();
    float a = word_b[tid];
    for (int k = 0; k < NC; k++) a += er[k] * word_w[(size_t)tid * NC + k];
    E[(size_t)row * HID + tid] = a;
}

// ---------------- row-major bf16 weight casts (+ wE_bf[256][320] enc-part of attn_w) ----------------
__global__ void k_prep(const float* __restrict__ attn_w, const float* __restrict__ out_w,
                       unsigned short* __restrict__ wA_bf, unsigned short* __restrict__ ow_bf,
                       unsigned short* __restrict__ wE_bf) {
    int o = blockIdx.x, k = threadIdx.x;
    wA_bf[(size_t)o * 256 + k] = f2bf(attn_w[(size_t)o * 552 + k]);
    if (o < NC) ow_bf[(size_t)o * 256 + k] = f2bf(out_w[(size_t)o * 256 + k]);
    for (int k2 = k; k2 < 320; k2 += 256)
        wE_bf[(size_t)o * 320 + k2] = (k2 < 296) ? f2bf(attn_w[(size_t)o * 552 + 256 + k2]) : 0;
}

// ---------------- gate weight packs, K-split ----------------
__global__ void __launch_bounds__(1024) k_wpack(const float* __restrict__ wih,
        const float* __restrict__ whh, unsigned short* __restrict__ WpackC,
        unsigned short* __restrict__ WpackH) {
    const int blk = blockIdx.x;   // 0..68
    const int tid = threadIdx.x;
    unsigned short o[8];
    if (blk < 37) {
        #pragma unroll
        for (int j = 0; j < 8; j++) {
            int k = blk * 8 + j;
            float v = (tid < 768) ? wih[(size_t)tid * 552 + 256 + k] : 0.f;
            o[j] = f2bf(v);
        }
        *reinterpret_cast<u16x8*>(WpackC + ((size_t)blk * 1024 + tid) * 8) =
            *reinterpret_cast<u16x8*>(o);
    } else {
        int it = blk - 37;
        #pragma unroll
        for (int j = 0; j < 8; j++) {
            int k = it * 8 + j;
            float v = (tid < 768) ? whh[(size_t)tid * 256 + k] : 0.f;
            o[j] = f2bf(v);
        }
        *reinterpret_cast<u16x8*>(WpackH + ((size_t)it * 1024 + tid) * 8) =
            *reinterpret_cast<u16x8*>(o);
    }
}

// WgE[k][g] = wih[g][k] (k<256, emb part, k-major bf16)
__global__ void __launch_bounds__(768) k_wge(const float* __restrict__ wih,
                                             unsigned short* __restrict__ WgE) {
    int k = blockIdx.x, g = threadIdx.x;
    WgE[(size_t)k * 768 + g] = f2bf(wih[(size_t)g * 552 + k]);
}
// giE[v][g] = sum_k WgE[k][g]*E[v][k] + bih[g]
__global__ void __launch_bounds__(768) k_gie(const float* __restrict__ E,
                                             const unsigned short* __restrict__ WgE,
                                             const float* __restrict__ bih,
                                             float* __restrict__ giE) {
    __shared__ float er[256];
    int v = blockIdx.x, g = threadIdx.x;
    if (g < 256) er[g] = E[(size_t)v * 256 + g];
    __syncthreads();
    float a = bih[g];
    #pragma unroll 4
    for (int k = 0; k < 256; k++) a += er[k] * bf2f(WgE[(size_t)k * 768 + g]);
    giE[(size_t)v * 768 + g] = a;
}

// ---------------- ep_t[b][l][h] via MFMA: ep = enc @ wE^T, K=296 padded to 320 ----------------
__global__ void __launch_bounds__(256) k_epmm(const unsigned short* __restrict__ enc_bf,
        const unsigned short* __restrict__ wE_bf, unsigned short* __restrict__ ep_t) {
    __shared__ __align__(16) unsigned short A_s[128 * TS];
    __shared__ __align__(16) unsigned short B_s[128 * TS];
    const int mt = blockIdx.x;           // 0..3: (ltile, ntile)
    const int b = blockIdx.y;
    const int l0 = (mt & 1) * 128;
    const int n0 = (mt >> 1) * 128;
    const int tid = threadIdx.x;
    const int wave = tid >> 6, lane = tid & 63;
    const int mq = (wave & 1) * 64, nq = (wave >> 1) * 64;
    const int lm = lane & 15, lq = lane >> 4;
    f32x4 acc[4][4];
    #pragma unroll
    for (int mi = 0; mi < 4; mi++)
        #pragma unroll
        for (int ni = 0; ni < 4; ni++)
            #pragma unroll
            for (int r = 0; r < 4; r++) acc[mi][ni][r] = 0.f;

    for (int kc = 0; kc < 320; kc += 32) {
        __syncthreads();
        #pragma unroll
        for (int it = 0; it < 2; it++) {
            int s2 = tid + it * 256;
            int row = s2 >> 2, q4 = s2 & 3;
            int k = kc + q4 * 8;
            u16x8 va = {0, 0, 0, 0, 0, 0, 0, 0};
            if (k < 296)   // 296 is 8-aligned -> full u16x8 loads only
                va = *reinterpret_cast<const u16x8*>(
                    enc_bf + (size_t)(b * L + l0 + row) * CENC + k);
            *reinterpret_cast<u16x8*>(A_s + row * TS + q4 * 8) = va;
            u16x8 vb = *reinterpret_cast<const u16x8*>(
                wE_bf + (size_t)(n0 + row) * 320 + k);
            *reinterpret_cast<u16x8*>(B_s + row * TS + q4 * 8) = vb;
        }
        __syncthreads();
        short8 af[4], bfr[4];
        #pragma unroll
        for (int mi = 0; mi < 4; mi++)
            af[mi] = *reinterpret_cast<const short8*>(A_s + (mq + mi * 16 + lm) * TS + lq * 8);
        #pragma unroll
        for (int ni = 0; ni < 4; ni++)
            bfr[ni] = *reinterpret_cast<const short8*>(B_s + (nq + ni * 16 + lm) * TS + lq * 8);
        #pragma unroll
        for (int mi = 0; mi < 4; mi++)
            #pragma unroll
            for (int ni = 0; ni < 4; ni++)
                acc[mi][ni] = __builtin_amdgcn_mfma_f32_16x16x32_bf16(
                    af[mi], bfr[ni], acc[mi][ni], 0, 0, 0);
    }
    #pragma unroll
    for (int mi = 0; mi < 4; mi++)
        #pragma unroll
        for (int ni = 0; ni < 4; ni++)
            #pragma unroll
            for (int r = 0; r < 4; r++) {
                int l = l0 + mq + mi * 16 + lq * 4 + r;
                int h = n0 + nq + ni * 16 + lm;
                ep_t[((size_t)b * L + l) * HID + h] = f2bf(acc[mi][ni][r]);
            }
}

// ---------------- zero the tagged mailboxes ----------------
__global__ void k_init(u64* __restrict__ hX64, u64* __restrict__ sX64) {
    int gi = blockIdx.x * 256 + threadIdx.x;          // 0..65535
    if (gi < B * 256) hX64[gi] = 0ull;
    else sX64[gi - B * 256] = 0ull;
}

// ---------------- paired persistent step loop: tagged u64 f32-payload mailbox ----------------
__global__ void __launch_bounds__(1024) k_steps(
        const float* __restrict__ giE, const float* __restrict__ bhh,
        const unsigned short* __restrict__ ep_t, const unsigned short* __restrict__ enc_t,
        const unsigned short* __restrict__ wA_bf, const unsigned short* __restrict__ ow_bf,
        const unsigned short* __restrict__ pos2t,
        const unsigned short* __restrict__ WpackC, const unsigned short* __restrict__ WpackH,
        const float* __restrict__ attn_b, const float* __restrict__ attn_v,
        const float* __restrict__ out_b,
        const int* __restrict__ dec_tgt, const int* __restrict__ word_tgt,
        float* __restrict__ nllG,
        u64* __restrict__ hX64, u64* __restrict__ sX64) {
    const int bid = blockIdx.x;
    const bool roleA = bid < B;
    const int b = bid & (B - 1);
    const int tid = threadIdx.x;
    const int hwid = tid >> 5, l32 = tid & 31;

    __shared__ __align__(16) unsigned short big[L * 256];   // 128 KB: ep (A) or enc (B)
    __shared__ __align__(16) float rinF[552];               // ctx f32 [0..295], h f32 [296..551] (B)
    __shared__ __align__(16) float hF[384];                 // h f32 padded (A)
    __shared__ __align__(16) float hpF[384], vbF[384], swlF[384];
    __shared__ float hfS[256];
    __shared__ float scr[256];
    __shared__ float red[16];
    __shared__ float rzS[512], inS[256], hnS[256];

    if (roleA) {
        // ---------------- role A: attention server + nll ----------------
        if (tid < 256) vbF[PH(tid)] = attn_v[tid];
        {
            const u16x8* src = reinterpret_cast<const u16x8*>(ep_t + (size_t)b * L * 256);
            u16x8* dst = reinterpret_cast<u16x8*>(big);
            #pragma unroll
            for (int i = 0; i < 8; i++) dst[tid + i * 1024] = src[tid + i * 1024];
        }
        float nllacc = 0.f;
        __syncthreads();
        for (int t = 0; t <= T; t++) {
            // recv h: per-lane tagged poll, f32 payload
            if (tid < 256) {
                u64 want = (u64)(t + 1);
                u64 v;
                for (;;) {
                    v = __hip_atomic_load(&hX64[b * 256 + tid], __ATOMIC_RELAXED,
                                          __HIP_MEMORY_SCOPE_AGENT);
                    if ((v >> 32) == want) break;
                    __builtin_amdgcn_s_sleep(1);
                }
                hF[PH(tid)] = __uint_as_float((unsigned int)v);
            }
            __syncthreads();
            if (t < T) {
                // s2: hp = h @ wA^T + attn_b
                {
                    float4 ha = *reinterpret_cast<const float4*>(hF + l32 * 12);
                    float4 hb = *reinterpret_cast<const float4*>(hF + l32 * 12 + 4);
                    #pragma unroll
                    for (int it = 0; it < 8; it++) {
                        int row = it * 32 + hwid;
                        u16x8 w = *reinterpret_cast<const u16x8*>(wA_bf + (size_t)row * 256 + l32 * 8);
                        float d = bf2f(w[0]) * ha.x + bf2f(w[1]) * ha.y
                                + bf2f(w[2]) * ha.z + bf2f(w[3]) * ha.w
                                + bf2f(w[4]) * hb.x + bf2f(w[5]) * hb.y
                                + bf2f(w[6]) * hb.z + bf2f(w[7]) * hb.w;
                        d = half_red_sum(d);
                        if (l32 == 0) hpF[PH(row)] = d + attn_b[row];
                    }
                }
                __syncthreads();
                // s3: scores (no-max softmax prep)
                {
                    float4 ha = *reinterpret_cast<const float4*>(hpF + l32 * 12);
                    float4 hb = *reinterpret_cast<const float4*>(hpF + l32 * 12 + 4);
                    float4 va = *reinterpret_cast<const float4*>(vbF + l32 * 12);
                    float4 vv = *reinterpret_cast<const float4*>(vbF + l32 * 12 + 4);
                    #pragma unroll
                    for (int it = 0; it < 8; it++) {
                        int row = it * 32 + hwid;
                        u16x8 e = *reinterpret_cast<const u16x8*>(big + (size_t)row * 256 + l32 * 8);
                        float d = va.x * fast_tanh(bf2f(e[0]) + ha.x)
                                + va.y * fast_tanh(bf2f(e[1]) + ha.y)
                                + va.z * fast_tanh(bf2f(e[2]) + ha.z)
                                + va.w * fast_tanh(bf2f(e[3]) + ha.w)
                                + vv.x * fast_tanh(bf2f(e[4]) + hb.x)
                                + vv.y * fast_tanh(bf2f(e[5]) + hb.y)
                                + vv.z * fast_tanh(bf2f(e[6]) + hb.z)
                                + vv.w * fast_tanh(bf2f(e[7]) + hb.w);
                        d = half_red_sum(d);
                        if (l32 == 0) scr[row] = d;
                    }
                }
                __syncthreads();
                // softmax without max-subtraction (scores bounded by sum|v| ~ 13)
                float e2 = 0.f;
                if (tid < 256) {
                    e2 = __expf(scr[tid]);
                    float sm = wave_red_sum(e2);
                    if ((tid & 63) == 0) red[8 + (tid >> 6)] = sm;
                }
                __syncthreads();
                // send softmax weights directly: tagged u64, f32 payload, no staging
                if (tid < 256) {
                    float invS = __builtin_amdgcn_rcpf(red[8] + red[9] + red[10] + red[11]);
                    float wv = e2 * invS;
                    __hip_atomic_store(&sX64[b * 256 + tid],
                                       ((u64)(t + 1) << 32) | (u64)__float_as_uint(wv),
                                       __ATOMIC_RELAXED, __HIP_MEMORY_SCOPE_AGENT);
                }
            }
            // s1 (off critical path): logits(h_t) + nll vs word_targets[t-1]
            if (t > 0) {
                float4 ha = *reinterpret_cast<const float4*>(hF + l32 * 12);
                float4 hb = *reinterpret_cast<const float4*>(hF + l32 * 12 + 4);
                #pragma unroll
                for (int it = 0; it < 6; it++) {
                    int row = it * 32 + hwid;
                    float d = 0.f;
                    if (row < NC) {
                        u16x8 w = *reinterpret_cast<const u16x8*>(ow_bf + (size_t)row * 256 + l32 * 8);
                        d = bf2f(w[0]) * ha.x + bf2f(w[1]) * ha.y
                          + bf2f(w[2]) * ha.z + bf2f(w[3]) * ha.w
                          + bf2f(w[4]) * hb.x + bf2f(w[5]) * hb.y
                          + bf2f(w[6]) * hb.z + bf2f(w[7]) * hb.w;
                    }
                    d = half_red_sum(d);
                    if (l32 == 0 && row < NC) scr[row] = d + out_b[row];
                }
                __syncthreads();
                float lg = -1e30f;
                if (tid < 256) {
                    if (tid < NC) lg = scr[tid];
                    float m = wave_red_max(lg);
                    if ((tid & 63) == 0) red[tid >> 6] = m;
                }
                __syncthreads();
                float M = fmaxf(fmaxf(red[0], red[1]), fmaxf(red[2], red[3]));
                if (tid < 256) {
                    float e = (tid < NC) ? __expf(lg - M) : 0.f;
                    float sm = wave_red_sum(e);
                    if ((tid & 63) == 0) red[8 + (tid >> 6)] = sm;
                }
                __syncthreads();
                if (tid == 0) {
                    float S = red[8] + red[9] + red[10] + red[11];
                    int tgt = word_tgt[b * T + (t - 1)];
                    if (tgt >= 0) nllacc += M + __logf(S) - scr[tgt];
                }
                __syncthreads();
            }
        }
        if (tid == 0) nllG[b] = nllacc;
    } else {
        // ---------------- role B: GRU worker ----------------
        {
            const u16x8* src = reinterpret_cast<const u16x8*>(enc_t + (size_t)b * 256 * 256);
            u16x8* dst = reinterpret_cast<u16x8*>(big);
            #pragma unroll
            for (int i = 0; i < 8; i++) dst[tid + i * 1024] = src[tid + i * 1024];
        }
        __syncthreads();
        for (int t = 0; t <= T; t++) {
            // s0: GRU pointwise h_t + immediate tagged send (before any barrier)
            if (tid < 256) {
                float h;
                if (t == 0) {
                    h = 0.f;
                } else {
                    float hold = hfS[tid];
                    int tokp = (t == 1) ? 0 : dec_tgt[b * T + (t - 2)];
                    const float* gE = giE + (size_t)tokp * 768;
                    float r_ = fast_sigm(rzS[tid] + gE[tid] + bhh[tid]);
                    float z_ = fast_sigm(rzS[256 + tid] + gE[256 + tid] + bhh[256 + tid]);
                    float n_ = fast_tanh(inS[tid] + gE[512 + tid] + r_ * (hnS[tid] + bhh[512 + tid]));
                    h = (1.f - z_) * n_ + z_ * hold;
                }
                __hip_atomic_store(&hX64[b * 256 + tid],
                                   ((u64)(t + 1) << 32) | (u64)__float_as_uint(h),
                                   __ATOMIC_RELAXED, __HIP_MEMORY_SCOPE_AGENT);
                hfS[tid] = h;
                rinF[296 + tid] = h;
            }
            __syncthreads();
            if (t == T) break;
            // h-part gates (overlaps A's s2/s3/softmax): hacc stays in a register
            float hacc = 0.f;
            if (tid < 768) {
                float a0 = 0.f, a1 = 0.f;
                #pragma unroll 4
                for (int it = 0; it < 32; it++) {
                    u16x8 w = *reinterpret_cast<const u16x8*>(WpackH + ((size_t)it * 1024 + tid) * 8);
                    float4 ra = *reinterpret_cast<const float4*>(rinF + 296 + it * 8);
                    float4 rb = *reinterpret_cast<const float4*>(rinF + 296 + it * 8 + 4);
                    a0 += bf2f(w[0]) * ra.x + bf2f(w[2]) * ra.z
                        + bf2f(w[4]) * rb.x + bf2f(w[6]) * rb.z;
                    a1 += bf2f(w[1]) * ra.y + bf2f(w[3]) * ra.w
                        + bf2f(w[5]) * rb.y + bf2f(w[7]) * rb.w;
                }
                hacc = a0 + a1;
            }
            // recv softmax weights: per-lane tagged poll, f32 payload
            if (tid < 256) {
                u64 want = (u64)(t + 1);
                u64 v;
                for (;;) {
                    v = __hip_atomic_load(&sX64[b * 256 + tid], __ATOMIC_RELAXED,
                                          __HIP_MEMORY_SCOPE_AGENT);
                    if ((v >> 32) == want) break;
                    __builtin_amdgcn_s_sleep(1);
                }
                swlF[PH(tid)] = __uint_as_float((unsigned int)v);
            }
            __syncthreads();
            // s4: ctx channels 0..255 from enc LDS (f32 result straight into rinF)
            {
                float4 sa = *reinterpret_cast<const float4*>(swlF + l32 * 12);
                float4 sb = *reinterpret_cast<const float4*>(swlF + l32 * 12 + 4);
                #pragma unroll
                for (int it = 0; it < 8; it++) {
                    int row = it * 32 + hwid;
                    u16x8 e = *reinterpret_cast<const u16x8*>(big + (size_t)row * 256 + l32 * 8);
                    float d = bf2f(e[0]) * sa.x + bf2f(e[1]) * sa.y
                            + bf2f(e[2]) * sa.z + bf2f(e[3]) * sa.w
                            + bf2f(e[4]) * sb.x + bf2f(e[5]) * sb.y
                            + bf2f(e[6]) * sb.z + bf2f(e[7]) * sb.w;
                    d = half_red_sum(d);
                    if (l32 == 0) rinF[row] = d;
                }
                // s4b: positional channels
                #pragma unroll
                for (int it = 0; it < 2; it++) {
                    int row = it * 32 + hwid;
                    float d = 0.f;
                    if (row < 40) {
                        u16x8 p = *reinterpret_cast<const u16x8*>(pos2t + (size_t)row * 256 + l32 * 8);
                        d = bf2f(p[0]) * sa.x + bf2f(p[1]) * sa.y
                          + bf2f(p[2]) * sa.z + bf2f(p[3]) * sa.w
                          + bf2f(p[4]) * sb.x + bf2f(p[5]) * sb.y
                          + bf2f(p[6]) * sb.z + bf2f(p[7]) * sb.w;
                    }
                    d = half_red_sum(d);
                    if (l32 == 0 && row < 40) rinF[256 + row] = d;
                }
            }
            __syncthreads();
            // ctx-part gates (critical path, 37 iters) + combine with hacc
            if (tid < 768) {
                float c0 = 0.f, c1 = 0.f;
                #pragma unroll 4
                for (int it = 0; it < 37; it++) {
                    u16x8 w = *reinterpret_cast<const u16x8*>(WpackC + ((size_t)it * 1024 + tid) * 8);
                    float4 ra = *reinterpret_cast<const float4*>(rinF + it * 8);
                    float4 rb = *reinterpret_cast<const float4*>(rinF + it * 8 + 4);
                    c0 += bf2f(w[0]) * ra.x + bf2f(w[2]) * ra.z
                        + bf2f(w[4]) * rb.x + bf2f(w[6]) * rb.z;
                    c1 += bf2f(w[1]) * ra.y + bf2f(w[3]) * ra.w
                        + bf2f(w[5]) * rb.y + bf2f(w[7]) * rb.w;
                }
                float cacc = c0 + c1;
                if (tid < 512) rzS[tid] = cacc + hacc;
                else { inS[tid - 512] = cacc; hnS[tid - 512] = hacc; }
            }
            __syncthreads();
        }
    }
}

// ---------------- loss = 0.2 * mean_b(nll) ----------------
__global__ void k_reduce(const float* __restrict__ nll, float* __restrict__ out) {
    __shared__ float red[2];
    float v = nll[threadIdx.x];
    v = wave_red_sum(v);
    if ((threadIdx.x & 63) == 0) red[threadIdx.x >> 6] = v;
    __syncthreads();
    if (threadIdx.x == 0) out[0] = 0.2f * (red[0] + red[1]) * (1.f / 128.f);
}

extern "C" void kernel_launch(void* const* d_in, const int* in_sizes, int n_in,
                              void* d_out, int out_size, void* d_ws, size_t ws_size,
                              hipStream_t stream) {
    const float* x        = (const float*)d_in[0];
    const int*   dec_tgt  = (const int*)d_in[1];
    const int*   word_tgt = (const int*)d_in[2];
    const float* conv_w   = (const float*)d_in[3];
    const float* conv_b   = (const float*)d_in[4];
    const float* emb_dec  = (const float*)d_in[5];
    const float* word_w   = (const float*)d_in[6];
    const float* word_b   = (const float*)d_in[7];
    const float* attn_w   = (const float*)d_in[8];
    const float* attn_b   = (const float*)d_in[9];
    const float* attn_v   = (const float*)d_in[10];
    const float* gru_wih  = (const float*)d_in[11];
    const float* gru_bih  = (const float*)d_in[12];
    const float* gru_whh  = (const float*)d_in[13];
    const float* gru_bhh  = (const float*)d_in[14];
    const float* out_w    = (const float*)d_in[15];
    const float* out_b    = (const float*)d_in[16];
    const float* x_emb    = (const float*)d_in[17];
    const float* y_emb    = (const float*)d_in[18];

    char* ws = (char*)d_ws;
    size_t off = 0;
    auto alloc = [&](size_t bytes) -> void* {
        void* p = ws + off;
        off = (off + bytes + 255) & ~(size_t)255;
        return p;
    };
    unsigned short* Xt     = (unsigned short*)alloc((size_t)B * 16 * 64 * 256 * 2);  // 67MB
    unsigned short* enc_bf = (unsigned short*)alloc((size_t)B * L * CENC * 2);        // 19.4MB
    unsigned short* Wt     = (unsigned short*)alloc((size_t)9 * 256 * 256 * 2);
    float* E      = (float*)alloc((size_t)NC * HID * 4);
    unsigned short* wA_bf  = (unsigned short*)alloc((size_t)HID * HID * 2);
    unsigned short* ow_bf  = (unsigned short*)alloc((size_t)NC * HID * 2);
    unsigned short* wE_bf  = (unsigned short*)alloc((size_t)HID * 320 * 2);
    unsigned short* WpackC = (unsigned short*)alloc((size_t)37 * 1024 * 8 * 2);       // 606KB
    unsigned short* WpackH = (unsigned short*)alloc((size_t)32 * 1024 * 8 * 2);       // 524KB
    unsigned short* WgE    = (unsigned short*)alloc((size_t)256 * 768 * 2);
    float* giE    = (float*)alloc((size_t)NC * 768 * 4);
    unsigned short* pos2t  = (unsigned short*)alloc((size_t)40 * 256 * 2);
    float* nllG   = (float*)alloc((size_t)B * 4);
    u64* hX64     = (u64*)alloc((size_t)B * 256 * 8);
    u64* sX64     = (u64*)alloc((size_t)B * 256 * 8);
    // ep_t / enc_t alias Xt (dead after k_convmm)
    unsigned short* ep_t  = Xt;
    unsigned short* enc_t = Xt + (size_t)B * L * HID;
    float* out    = (float*)d_out;

    hipLaunchKernelGGL(k_init, dim3(256), dim3(256), 0, stream, hX64, sX64);
    hipLaunchKernelGGL(k_upsxt, dim3(16, 128), dim3(256), 0, stream, x, Xt);
    hipLaunchKernelGGL(k_wt, dim3(2304), dim3(256), 0, stream, conv_w, Wt);
    hipLaunchKernelGGL(k_encpos, dim3(128), dim3(256), 0, stream, x_emb, y_emb, enc_bf, pos2t);
    hipLaunchKernelGGL(k_convmm, dim3(1024, 2), dim3(256), 0, stream, Xt, Wt, conv_b, enc_bf);
    hipLaunchKernelGGL(k_etab, dim3(163), dim3(256), 0, stream, emb_dec, word_w, word_b, E);
    hipLaunchKernelGGL(k_prep, dim3(256), dim3(256), 0, stream, attn_w, out_w, wA_bf, ow_bf, wE_bf);
    hipLaunchKernelGGL(k_wpack, dim3(69), dim3(1024), 0, stream, gru_wih, gru_whh, WpackC, WpackH);
    hipLaunchKernelGGL(k_wge, dim3(256), dim3(768), 0, stream, gru_wih, WgE);
    hipLaunchKernelGGL(k_gie, dim3(163), dim3(768), 0, stream, E, WgE, gru_bih, giE);
    hipLaunchKernelGGL(k_epmm, dim3(4, 128), dim3(256), 0, stream, enc_bf, wE_bf, ep_t);
    hipLaunchKernelGGL(k_enct, dim3(4, 128), dim3(256), 0, stream, enc_bf, enc_t);
    hipLaunchKernelGGL(k_steps, dim3(256), dim3(1024), 0, stream,
                       giE, gru_bhh, ep_t, enc_t, wA_bf, ow_bf, pos2t, WpackC, WpackH,
                       attn_b, attn_v, out_b, dec_tgt, word_tgt, nllG,
                       hX64, sX64);
    hipLaunchKernelGGL(k_reduce, dim3(1), dim3(128), 0, stream, nllG, out);
}

// Round 14
// 1044.333 us; speedup vs baseline: 1.5186x; 1.5186x over previous
//
#include <hip/hip_runtime.h>
#include <hip/hip_bf16.h>
#include <math.h>

#define B    128
#define CIN  256
#define HIN  8
#define WIN_ 32
#define RH   16
#define RW   64
#define HID  256
#define NC   163
#define T    32
#define L    256
#define CENC 296

typedef __attribute__((ext_vector_type(8))) short short8;
typedef __attribute__((ext_vector_type(8))) unsigned short u16x8;
typedef __attribute__((ext_vector_type(4))) float f32x4;
typedef unsigned long long u64;

// padded f32 mirror addressing: group of 8 floats stored in 12-float slot (48B, 16B-aligned)
#define PH(k) ((((k) >> 3) * 12) + ((k) & 7))
// LDS tile row stride (shorts). 40 = 80B: 16B-aligned rows, 2-way bank alias (free, m136).
// NOTE r13: 44 removed conflicts but broke b128 alignment (3x regression). Keep 40.
#define TS 40

__device__ __forceinline__ float bf2f(unsigned short u) {
    unsigned int x = ((unsigned int)u) << 16;
    return __uint_as_float(x);
}
__device__ __forceinline__ unsigned short f2bf(float f) {
    unsigned int x = __float_as_uint(f);
    unsigned int r = (x + 0x7FFFu + ((x >> 16) & 1u)) >> 16;
    return (unsigned short)r;
}
__device__ __forceinline__ float fast_tanh(float x) {
    float e = __expf(2.f * x);
    return 1.f - 2.f * __builtin_amdgcn_rcpf(e + 1.f);
}
__device__ __forceinline__ float fast_sigm(float x) {
    return __builtin_amdgcn_rcpf(1.f + __expf(-x));
}
__device__ __forceinline__ float wave_red_max(float v) {
    #pragma unroll
    for (int o = 32; o > 0; o >>= 1) v = fmaxf(v, __shfl_down(v, o, 64));
    return v;
}
__device__ __forceinline__ float wave_red_sum(float v) {
    #pragma unroll
    for (int o = 32; o > 0; o >>= 1) v += __shfl_down(v, o, 64);
    return v;
}
__device__ __forceinline__ float half_red_sum(float v) {
    #pragma unroll
    for (int o = 16; o > 0; o >>= 1) v += __shfl_down(v, o, 64);
    return v;
}

// ---------------- bilinear upsample fused with transpose → Xt[b][y][x][ci] bf16 ----------------
__global__ void __launch_bounds__(256) k_upsxt(const float* __restrict__ x,
                                               unsigned short* __restrict__ Xt) {
    __shared__ __align__(16) float sf[64 * 2 * 32];
    const int y = blockIdx.x;
    const int b = blockIdx.y;
    const int tid = threadIdx.x;
    float sy = 0.5f * y - 0.25f;
    int yq0 = (y - 1) >> 1;
    float wy = sy - (float)yq0;
    int y0c = min(max(yq0, 0), HIN - 1);
    int y1c = min(max(yq0 + 1, 0), HIN - 1);
    const int xo = tid & 63;
    const int cj = tid >> 6;
    float sx = 0.5f * xo - 0.25f;
    int xq0 = (xo - 1) >> 1;
    float wx = sx - (float)xq0;
    int x0c = min(max(xq0, 0), WIN_ - 1);
    int x1c = min(max(xq0 + 1, 0), WIN_ - 1);
    for (int cc = 0; cc < 4; cc++) {
        __syncthreads();
        #pragma unroll
        for (int i = 0; i < 4; i++) {
            int idx = tid * 4 + i;
            int c = idx >> 4;
            int rowh = (idx >> 3) & 1;
            int part = idx & 7;
            int ysrc = rowh ? y1c : y0c;
            float4 v = *reinterpret_cast<const float4*>(
                x + ((size_t)(b * CIN + cc * 64 + c) * HIN + ysrc) * WIN_ + part * 4);
            *reinterpret_cast<float4*>(sf + ((c * 2 + rowh) * 32 + part * 4)) = v;
        }
        __syncthreads();
        unsigned short ov[16];
        #pragma unroll
        for (int j = 0; j < 16; j++) {
            int c = cj * 16 + j;
            const float* r0 = sf + (c * 2 + 0) * 32;
            const float* r1 = sf + (c * 2 + 1) * 32;
            float v = (1.f - wy) * ((1.f - wx) * r0[x0c] + wx * r0[x1c])
                    +        wy  * ((1.f - wx) * r1[x0c] + wx * r1[x1c]);
            ov[j] = f2bf(v);
        }
        unsigned short* dst = Xt + ((size_t)((b * 16 + y) * 64 + xo)) * 256 + cc * 64 + cj * 16;
        *reinterpret_cast<u16x8*>(dst)     = *reinterpret_cast<u16x8*>(ov);
        *reinterpret_cast<u16x8*>(dst + 8) = *reinterpret_cast<u16x8*>(ov + 8);
    }
}

// ---------------- fused independent prep: init + wt + encpos + etab + prep + wpack + wge ----------------
// blockIdx ranges: [0,256) init, [256,2560) wt, [2560,2688) encpos, [2688,2851) etab,
// [2851,3107) prep, [3107,3383) wpack(69x4), [3383,4151) wge(256x3). 256 threads each.
__global__ void __launch_bounds__(256) k_preall(
        const float* __restrict__ conv_w, const float* __restrict__ x_emb,
        const float* __restrict__ y_emb, const float* __restrict__ emb_dec,
        const float* __restrict__ word_w, const float* __restrict__ word_b,
        const float* __restrict__ attn_w, const float* __restrict__ out_w,
        const float* __restrict__ wih, const float* __restrict__ whh,
        unsigned short* __restrict__ Wt, unsigned short* __restrict__ enc_bf,
        unsigned short* __restrict__ pos2t, float* __restrict__ E,
        unsigned short* __restrict__ wA_bf, unsigned short* __restrict__ ow_bf,
        unsigned short* __restrict__ wE_bf, unsigned short* __restrict__ WpackC,
        unsigned short* __restrict__ WpackH, unsigned short* __restrict__ WgE,
        u64* __restrict__ hX64, u64* __restrict__ sX64) {
    int blk = blockIdx.x;
    const int tid = threadIdx.x;
    if (blk < 256) {                       // ---- init mailboxes
        int gi = blk * 256 + tid;
        if (gi < B * 256) hX64[gi] = 0ull;
        else sX64[gi - B * 256] = 0ull;
        return;
    }
    blk -= 256;
    if (blk < 2304) {                      // ---- k_wt
        int e = blk * 256 + tid;
        int ci = e & 255;
        int co = (e >> 8) & 255;
        int s  = e >> 16;
        Wt[(size_t)(s * 256 + co) * 256 + ci] = f2bf(conv_w[(size_t)(co * 256 + ci) * 9 + s]);
        return;
    }
    blk -= 2304;
    if (blk < 128) {                       // ---- k_encpos
        int b = blk, l = tid;
        int yl = l >> 5, xl = l & 31;
        unsigned short* e = enc_bf + (size_t)(b * L + l) * CENC + 256;
        #pragma unroll
        for (int c = 0; c < 32; c++) e[c] = f2bf(x_emb[xl * 32 + c]);
        #pragma unroll
        for (int c = 0; c < 8; c++) e[32 + c] = f2bf(y_emb[yl * 8 + c]);
        if (b == 0) {
            #pragma unroll
            for (int c = 0; c < 32; c++) pos2t[c * 256 + l] = f2bf(x_emb[xl * 32 + c]);
            #pragma unroll
            for (int c = 0; c < 8; c++) pos2t[(32 + c) * 256 + l] = f2bf(y_emb[yl * 8 + c]);
        }
        return;
    }
    blk -= 128;
    if (blk < NC) {                        // ---- k_etab
        __shared__ float er[NC];
        int row = blk;
        for (int k = tid; k < NC; k += 256) er[k] = emb_dec[(size_t)row * NC + k];
        __syncthreads();
        float a = word_b[tid];
        for (int k = 0; k < NC; k++) a += er[k] * word_w[(size_t)tid * NC + k];
        E[(size_t)row * HID + tid] = a;
        return;
    }
    blk -= NC;
    if (blk < 256) {                       // ---- k_prep
        int o = blk, k = tid;
        wA_bf[(size_t)o * 256 + k] = f2bf(attn_w[(size_t)o * 552 + k]);
        if (o < NC) ow_bf[(size_t)o * 256 + k] = f2bf(out_w[(size_t)o * 256 + k]);
        for (int k2 = k; k2 < 320; k2 += 256)
            wE_bf[(size_t)o * 320 + k2] = (k2 < 296) ? f2bf(attn_w[(size_t)o * 552 + 256 + k2]) : 0;
        return;
    }
    blk -= 256;
    if (blk < 276) {                       // ---- k_wpack (69 orig blocks x 4 quarters)
        int obk = blk >> 2;                // 0..68
        int t1024 = (blk & 3) * 256 + tid; // 0..1023
        unsigned short o[8];
        if (obk < 37) {
            #pragma unroll
            for (int j = 0; j < 8; j++) {
                int k = obk * 8 + j;
                float v = (t1024 < 768) ? wih[(size_t)t1024 * 552 + 256 + k] : 0.f;
                o[j] = f2bf(v);
            }
            *reinterpret_cast<u16x8*>(WpackC + ((size_t)obk * 1024 + t1024) * 8) =
                *reinterpret_cast<u16x8*>(o);
        } else {
            int it = obk - 37;
            #pragma unroll
            for (int j = 0; j < 8; j++) {
                int k = it * 8 + j;
                float v = (t1024 < 768) ? whh[(size_t)t1024 * 256 + k] : 0.f;
                o[j] = f2bf(v);
            }
            *reinterpret_cast<u16x8*>(WpackH + ((size_t)it * 1024 + t1024) * 8) =
                *reinterpret_cast<u16x8*>(o);
        }
        return;
    }
    blk -= 276;
    {                                      // ---- k_wge (256 k-values x 3 g-chunks)
        int k = blk / 3;
        int g = (blk % 3) * 256 + tid;
        WgE[(size_t)k * 768 + g] = f2bf(wih[(size_t)g * 552 + k]);
    }
}

// ---------------- conv3x3 MFMA implicit GEMM + fused bias/ReLU/pool → enc_bf ----------------
__global__ void __launch_bounds__(256) k_convmm(const unsigned short* __restrict__ Xt,
        const unsigned short* __restrict__ Wt, const float* __restrict__ conv_b,
        unsigned short* __restrict__ enc_bf) {
    __shared__ __align__(16) char smem[34048];
    unsigned short* A_s = (unsigned short*)smem;
    unsigned short* B_s = A_s + 128 * TS;
    float* pool = (float*)smem;
    const int mt = blockIdx.x;
    const int n0 = blockIdx.y * 128;
    const int b = mt >> 3;
    const int y0 = (mt & 7) * 2;
    const int tid = threadIdx.x;
    const int wave = tid >> 6, lane = tid & 63;
    const int mq = (wave & 1) * 64, nq = (wave >> 1) * 64;
    const int lm = lane & 15, lq = lane >> 4;
    f32x4 acc[4][4];
    #pragma unroll
    for (int mi = 0; mi < 4; mi++)
        #pragma unroll
        for (int ni = 0; ni < 4; ni++)
            #pragma unroll
            for (int r = 0; r < 4; r++) acc[mi][ni][r] = 0.f;

    for (int s9 = 0; s9 < 9; s9++) {
        const int ky = s9 / 3, kx = s9 % 3;
        const unsigned short* Wb = Wt + (size_t)s9 * 256 * 256;
        for (int kc = 0; kc < 256; kc += 32) {
            __syncthreads();
            #pragma unroll
            for (int it = 0; it < 2; it++) {
                int s2 = tid + it * 256;
                int pix = s2 >> 2, q4 = s2 & 3;
                int yy = y0 + (pix >> 6) + ky - 1;
                int xx = (pix & 63) + kx - 1;
                u16x8 va = {0, 0, 0, 0, 0, 0, 0, 0};
                if ((unsigned)yy < 16u && (unsigned)xx < 64u)
                    va = *reinterpret_cast<const u16x8*>(
                        Xt + ((size_t)((b * 16 + yy) * 64 + xx)) * 256 + kc + q4 * 8);
                *reinterpret_cast<u16x8*>(A_s + pix * TS + q4 * 8) = va;
                u16x8 vb = *reinterpret_cast<const u16x8*>(
                    Wb + (size_t)(n0 + pix) * 256 + kc + q4 * 8);
                *reinterpret_cast<u16x8*>(B_s + pix * TS + q4 * 8) = vb;
            }
            __syncthreads();
            short8 af[4], bfr[4];
            #pragma unroll
            for (int mi = 0; mi < 4; mi++)
                af[mi] = *reinterpret_cast<const short8*>(A_s + (mq + mi * 16 + lm) * TS + lq * 8);
            #pragma unroll
            for (int ni = 0; ni < 4; ni++)
                bfr[ni] = *reinterpret_cast<const short8*>(B_s + (nq + ni * 16 + lm) * TS + lq * 8);
            #pragma unroll
            for (int mi = 0; mi < 4; mi++)
                #pragma unroll
                for (int ni = 0; ni < 4; ni++)
                    acc[mi][ni] = __builtin_amdgcn_mfma_f32_16x16x32_bf16(
                        af[mi], bfr[ni], acc[mi][ni], 0, 0, 0);
        }
    }
    __syncthreads();
    #pragma unroll
    for (int mi = 0; mi < 4; mi++) {
        int px0 = mi * 8 + lq * 2;
        #pragma unroll
        for (int ni = 0; ni < 4; ni++) {
            int nl = nq + ni * 16 + lm;
            float pa = fmaxf(acc[mi][ni][0], acc[mi][ni][1]);
            float pb = fmaxf(acc[mi][ni][2], acc[mi][ni][3]);
            pool[((wave & 1) * 32 + px0) * 132 + nl] = pa;
            pool[((wave & 1) * 32 + px0 + 1) * 132 + nl] = pb;
        }
    }
    __syncthreads();
    {
        int base = tid * 16;
        int px = base >> 7;
        int nb = base & 127;
        unsigned short ov[16];
        #pragma unroll
        for (int i = 0; i < 16; i++) {
            int n = nb + i;
            float v = fmaxf(pool[px * 132 + n], pool[(32 + px) * 132 + n]) + conv_b[n0 + n];
            ov[i] = f2bf(fmaxf(v, 0.f));
        }
        unsigned short* dst = enc_bf + ((size_t)b * L + (mt & 7) * 32 + px) * CENC + n0 + nb;
        *reinterpret_cast<u16x8*>(dst)     = *reinterpret_cast<u16x8*>(ov);
        *reinterpret_cast<u16x8*>(dst + 8) = *reinterpret_cast<u16x8*>(ov + 8);
    }
}

// giE[v][g] = sum_k WgE[k][g]*E[v][k] + bih[g]
__global__ void __launch_bounds__(768) k_gie(const float* __restrict__ E,
                                             const unsigned short* __restrict__ WgE,
                                             const float* __restrict__ bih,
                                             float* __restrict__ giE) {
    __shared__ float er[256];
    int v = blockIdx.x, g = threadIdx.x;
    if (g < 256) er[g] = E[(size_t)v * 256 + g];
    __syncthreads();
    float a = bih[g];
    #pragma unroll 4
    for (int k = 0; k < 256; k++) a += er[k] * bf2f(WgE[(size_t)k * 768 + g]);
    giE[(size_t)v * 768 + g] = a;
}

// ---------------- fused: epmm (blockIdx.x<4) + enct (blockIdx.x>=4) ----------------
// epmm: ep = enc @ wE^T via MFMA (K=296 padded to 320), convmm's verified mapping.
// enct: enc_t[b][c][l] transpose.
__global__ void __launch_bounds__(256) k_epenct(const unsigned short* __restrict__ enc_bf,
        const unsigned short* __restrict__ wE_bf, unsigned short* __restrict__ ep_t,
        unsigned short* __restrict__ enc_t) {
    __shared__ __align__(16) char smem2[33792];
    const int bx = blockIdx.x;
    const int b = blockIdx.y;
    const int tid = threadIdx.x;
    if (bx < 4) {
        unsigned short* A_s = (unsigned short*)smem2;
        unsigned short* B_s = A_s + 128 * TS;
        const int l0 = (bx & 1) * 128;
        const int n0 = (bx >> 1) * 128;
        const int wave = tid >> 6, lane = tid & 63;
        const int mq = (wave & 1) * 64, nq = (wave >> 1) * 64;
        const int lm = lane & 15, lq = lane >> 4;
        f32x4 acc[4][4];
        #pragma unroll
        for (int mi = 0; mi < 4; mi++)
            #pragma unroll
            for (int ni = 0; ni < 4; ni++)
                #pragma unroll
                for (int r = 0; r < 4; r++) acc[mi][ni][r] = 0.f;

        for (int kc = 0; kc < 320; kc += 32) {
            __syncthreads();
            #pragma unroll
            for (int it = 0; it < 2; it++) {
                int s2 = tid + it * 256;
                int row = s2 >> 2, q4 = s2 & 3;
                int k = kc + q4 * 8;
                u16x8 va = {0, 0, 0, 0, 0, 0, 0, 0};
                if (k < 296)   // 296 is 8-aligned -> full u16x8 loads only
                    va = *reinterpret_cast<const u16x8*>(
                        enc_bf + (size_t)(b * L + l0 + row) * CENC + k);
                *reinterpret_cast<u16x8*>(A_s + row * TS + q4 * 8) = va;
                u16x8 vb = *reinterpret_cast<const u16x8*>(
                    wE_bf + (size_t)(n0 + row) * 320 + k);
                *reinterpret_cast<u16x8*>(B_s + row * TS + q4 * 8) = vb;
            }
            __syncthreads();
            short8 af[4], bfr[4];
            #pragma unroll
            for (int mi = 0; mi < 4; mi++)
                af[mi] = *reinterpret_cast<const short8*>(A_s + (mq + mi * 16 + lm) * TS + lq * 8);
            #pragma unroll
            for (int ni = 0; ni < 4; ni++)
                bfr[ni] = *reinterpret_cast<const short8*>(B_s + (nq + ni * 16 + lm) * TS + lq * 8);
            #pragma unroll
            for (int mi = 0; mi < 4; mi++)
                #pragma unroll
                for (int ni = 0; ni < 4; ni++)
                    acc[mi][ni] = __builtin_amdgcn_mfma_f32_16x16x32_bf16(
                        af[mi], bfr[ni], acc[mi][ni], 0, 0, 0);
        }
        #pragma unroll
        for (int mi = 0; mi < 4; mi++)
            #pragma unroll
            for (int ni = 0; ni < 4; ni++)
                #pragma unroll
                for (int r = 0; r < 4; r++) {
                    int l = l0 + mq + mi * 16 + lq * 4 + r;
                    int h = n0 + nq + ni * 16 + lm;
                    ep_t[((size_t)b * L + l) * HID + h] = f2bf(acc[mi][ni][r]);
                }
    } else {
        unsigned short* s = (unsigned short*)smem2;   // [64][264]
        const int c0 = (bx - 4) * 64;
        #pragma unroll
        for (int j = 0; j < 8; j++) {
            u16x8 u = *reinterpret_cast<const u16x8*>(
                enc_bf + ((size_t)b * L + tid) * CENC + c0 + j * 8);
            #pragma unroll
            for (int k = 0; k < 8; k++) s[(j * 8 + k) * 264 + tid] = u[k];
        }
        __syncthreads();
        {
            int c = tid >> 2, lp = tid & 3;
            const unsigned short* row = s + c * 264 + lp * 64;
            unsigned short* dst = enc_t + ((size_t)b * 256 + c0 + c) * L + lp * 64;
            #pragma unroll
            for (int i = 0; i < 8; i++)
                *reinterpret_cast<u16x8*>(dst + i * 8) =
                    *reinterpret_cast<const u16x8*>(row + i * 8);
        }
    }
}

// ---------------- paired persistent step loop: tagged u64 f32-payload mailbox ----------------
__global__ void __launch_bounds__(1024) k_steps(
        const float* __restrict__ giE, const float* __restrict__ bhh,
        const unsigned short* __restrict__ ep_t, const unsigned short* __restrict__ enc_t,
        const unsigned short* __restrict__ wA_bf, const unsigned short* __restrict__ ow_bf,
        const unsigned short* __restrict__ pos2t,
        const unsigned short* __restrict__ WpackC, const unsigned short* __restrict__ WpackH,
        const float* __restrict__ attn_b, const float* __restrict__ attn_v,
        const float* __restrict__ out_b,
        const int* __restrict__ dec_tgt, const int* __restrict__ word_tgt,
        float* __restrict__ nllG,
        u64* __restrict__ hX64, u64* __restrict__ sX64) {
    const int bid = blockIdx.x;
    const bool roleA = bid < B;
    const int b = bid & (B - 1);
    const int tid = threadIdx.x;
    const int hwid = tid >> 5, l32 = tid & 31;

    __shared__ __align__(16) unsigned short big[L * 256];   // 128 KB: ep (A) or enc (B)
    __shared__ __align__(16) float rinF[552];               // ctx f32 [0..295], h f32 [296..551] (B)
    __shared__ __align__(16) float hF[384];                 // h f32 padded (A)
    __shared__ __align__(16) float hpF[384], vbF[384], swlF[384];
    __shared__ float hfS[256];
    __shared__ float scr[256];
    __shared__ float red[16];
    __shared__ float rzS[512], inS[256], hnS[256];

    if (roleA) {
        // ---------------- role A: attention server + nll ----------------
        if (tid < 256) vbF[PH(tid)] = attn_v[tid];
        {
            const u16x8* src = reinterpret_cast<const u16x8*>(ep_t + (size_t)b * L * 256);
            u16x8* dst = reinterpret_cast<u16x8*>(big);
            #pragma unroll
            for (int i = 0; i < 8; i++) dst[tid + i * 1024] = src[tid + i * 1024];
        }
        float nllacc = 0.f;
        __syncthreads();
        for (int t = 0; t <= T; t++) {
            // recv h: per-lane tagged poll, f32 payload
            if (tid < 256) {
                u64 want = (u64)(t + 1);
                u64 v;
                for (;;) {
                    v = __hip_atomic_load(&hX64[b * 256 + tid], __ATOMIC_RELAXED,
                                          __HIP_MEMORY_SCOPE_AGENT);
                    if ((v >> 32) == want) break;
                    __builtin_amdgcn_s_sleep(1);
                }
                hF[PH(tid)] = __uint_as_float((unsigned int)v);
            }
            __syncthreads();
            if (t < T) {
                // s2: hp = h @ wA^T + attn_b
                {
                    float4 ha = *reinterpret_cast<const float4*>(hF + l32 * 12);
                    float4 hb = *reinterpret_cast<const float4*>(hF + l32 * 12 + 4);
                    #pragma unroll
                    for (int it = 0; it < 8; it++) {
                        int row = it * 32 + hwid;
                        u16x8 w = *reinterpret_cast<const u16x8*>(wA_bf + (size_t)row * 256 + l32 * 8);
                        float d = bf2f(w[0]) * ha.x + bf2f(w[1]) * ha.y
                                + bf2f(w[2]) * ha.z + bf2f(w[3]) * ha.w
                                + bf2f(w[4]) * hb.x + bf2f(w[5]) * hb.y
                                + bf2f(w[6]) * hb.z + bf2f(w[7]) * hb.w;
                        d = half_red_sum(d);
                        if (l32 == 0) hpF[PH(row)] = d + attn_b[row];
                    }
                }
                __syncthreads();
                // s3: scores (no-max softmax prep)
                {
                    float4 ha = *reinterpret_cast<const float4*>(hpF + l32 * 12);
                    float4 hb = *reinterpret_cast<const float4*>(hpF + l32 * 12 + 4);
                    float4 va = *reinterpret_cast<const float4*>(vbF + l32 * 12);
                    float4 vv = *reinterpret_cast<const float4*>(vbF + l32 * 12 + 4);
                    #pragma unroll
                    for (int it = 0; it < 8; it++) {
                        int row = it * 32 + hwid;
                        u16x8 e = *reinterpret_cast<const u16x8*>(big + (size_t)row * 256 + l32 * 8);
                        float d = va.x * fast_tanh(bf2f(e[0]) + ha.x)
                                + va.y * fast_tanh(bf2f(e[1]) + ha.y)
                                + va.z * fast_tanh(bf2f(e[2]) + ha.z)
                                + va.w * fast_tanh(bf2f(e[3]) + ha.w)
                                + vv.x * fast_tanh(bf2f(e[4]) + hb.x)
                                + vv.y * fast_tanh(bf2f(e[5]) + hb.y)
                                + vv.z * fast_tanh(bf2f(e[6]) + hb.z)
                                + vv.w * fast_tanh(bf2f(e[7]) + hb.w);
                        d = half_red_sum(d);
                        if (l32 == 0) scr[row] = d;
                    }
                }
                __syncthreads();
                // softmax without max-subtraction (scores bounded by sum|v| ~ 13)
                float e2 = 0.f;
                if (tid < 256) {
                    e2 = __expf(scr[tid]);
                    float sm = wave_red_sum(e2);
                    if ((tid & 63) == 0) red[8 + (tid >> 6)] = sm;
                }
                __syncthreads();
                // send softmax weights directly: tagged u64, f32 payload, no staging
                if (tid < 256) {
                    float invS = __builtin_amdgcn_rcpf(red[8] + red[9] + red[10] + red[11]);
                    float wv = e2 * invS;
                    __hip_atomic_store(&sX64[b * 256 + tid],
                                       ((u64)(t + 1) << 32) | (u64)__float_as_uint(wv),
                                       __ATOMIC_RELAXED, __HIP_MEMORY_SCOPE_AGENT);
                }
            }
            // s1 (off critical path): logits(h_t) + nll vs word_targets[t-1]
            if (t > 0) {
                float4 ha = *reinterpret_cast<const float4*>(hF + l32 * 12);
                float4 hb = *reinterpret_cast<const float4*>(hF + l32 * 12 + 4);
                #pragma unroll
                for (int it = 0; it < 6; it++) {
                    int row = it * 32 + hwid;
                    float d = 0.f;
                    if (row < NC) {
                        u16x8 w = *reinterpret_cast<const u16x8*>(ow_bf + (size_t)row * 256 + l32 * 8);
                        d = bf2f(w[0]) * ha.x + bf2f(w[1]) * ha.y
                          + bf2f(w[2]) * ha.z + bf2f(w[3]) * ha.w
                          + bf2f(w[4]) * hb.x + bf2f(w[5]) * hb.y
                          + bf2f(w[6]) * hb.z + bf2f(w[7]) * hb.w;
                    }
                    d = half_red_sum(d);
                    if (l32 == 0 && row < NC) scr[row] = d + out_b[row];
                }
                __syncthreads();
                float lg = -1e30f;
                if (tid < 256) {
                    if (tid < NC) lg = scr[tid];
                    float m = wave_red_max(lg);
                    if ((tid & 63) == 0) red[tid >> 6] = m;
                }
                __syncthreads();
                float M = fmaxf(fmaxf(red[0], red[1]), fmaxf(red[2], red[3]));
                if (tid < 256) {
                    float e = (tid < NC) ? __expf(lg - M) : 0.f;
                    float sm = wave_red_sum(e);
                    if ((tid & 63) == 0) red[8 + (tid >> 6)] = sm;
                }
                __syncthreads();
                if (tid == 0) {
                    float S = red[8] + red[9] + red[10] + red[11];
                    int tgt = word_tgt[b * T + (t - 1)];
                    if (tgt >= 0) nllacc += M + __logf(S) - scr[tgt];
                }
                __syncthreads();
            }
        }
        if (tid == 0) nllG[b] = nllacc;
    } else {
        // ---------------- role B: GRU worker ----------------
        {
            const u16x8* src = reinterpret_cast<const u16x8*>(enc_t + (size_t)b * 256 * 256);
            u16x8* dst = reinterpret_cast<u16x8*>(big);
            #pragma unroll
            for (int i = 0; i < 8; i++) dst[tid + i * 1024] = src[tid + i * 1024];
        }
        __syncthreads();
        for (int t = 0; t <= T; t++) {
            // s0: GRU pointwise h_t + immediate tagged send (before any barrier)
            if (tid < 256) {
                float h;
                if (t == 0) {
                    h = 0.f;
                } else {
                    float hold = hfS[tid];
                    int tokp = (t == 1) ? 0 : dec_tgt[b * T + (t - 2)];
                    const float* gE = giE + (size_t)tokp * 768;
                    float r_ = fast_sigm(rzS[tid] + gE[tid] + bhh[tid]);
                    float z_ = fast_sigm(rzS[256 + tid] + gE[256 + tid] + bhh[256 + tid]);
                    float n_ = fast_tanh(inS[tid] + gE[512 + tid] + r_ * (hnS[tid] + bhh[512 + tid]));
                    h = (1.f - z_) * n_ + z_ * hold;
                }
                __hip_atomic_store(&hX64[b * 256 + tid],
                                   ((u64)(t + 1) << 32) | (u64)__float_as_uint(h),
                                   __ATOMIC_RELAXED, __HIP_MEMORY_SCOPE_AGENT);
                hfS[tid] = h;
                rinF[296 + tid] = h;
            }
            __syncthreads();
            if (t == T) break;
            // h-part gates (overlaps A's s2/s3/softmax): hacc stays in a register
            float hacc = 0.f;
            if (tid < 768) {
                float a0 = 0.f, a1 = 0.f;
                #pragma unroll 4
                for (int it = 0; it < 32; it++) {
                    u16x8 w = *reinterpret_cast<const u16x8*>(WpackH + ((size_t)it * 1024 + tid) * 8);
                    float4 ra = *reinterpret_cast<const float4*>(rinF + 296 + it * 8);
                    float4 rb = *reinterpret_cast<const float4*>(rinF + 296 + it * 8 + 4);
                    a0 += bf2f(w[0]) * ra.x + bf2f(w[2]) * ra.z
                        + bf2f(w[4]) * rb.x + bf2f(w[6]) * rb.z;
                    a1 += bf2f(w[1]) * ra.y + bf2f(w[3]) * ra.w
                        + bf2f(w[5]) * rb.y + bf2f(w[7]) * rb.w;
                }
                hacc = a0 + a1;
            }
            // recv softmax weights: per-lane tagged poll, f32 payload
            if (tid < 256) {
                u64 want = (u64)(t + 1);
                u64 v;
                for (;;) {
                    v = __hip_atomic_load(&sX64[b * 256 + tid], __ATOMIC_RELAXED,
                                          __HIP_MEMORY_SCOPE_AGENT);
                    if ((v >> 32) == want) break;
                    __builtin_amdgcn_s_sleep(1);
                }
                swlF[PH(tid)] = __uint_as_float((unsigned int)v);
            }
            __syncthreads();
            // s4: ctx channels 0..255 from enc LDS (f32 result straight into rinF)
            {
                float4 sa = *reinterpret_cast<const float4*>(swlF + l32 * 12);
                float4 sb = *reinterpret_cast<const float4*>(swlF + l32 * 12 + 4);
                #pragma unroll
                for (int it = 0; it < 8; it++) {
                    int row = it * 32 + hwid;
                    u16x8 e = *reinterpret_cast<const u16x8*>(big + (size_t)row * 256 + l32 * 8);
                    float d = bf2f(e[0]) * sa.x + bf2f(e[1]) * sa.y
                            + bf2f(e[2]) * sa.z + bf2f(e[3]) * sa.w
                            + bf2f(e[4]) * sb.x + bf2f(e[5]) * sb.y
                            + bf2f(e[6]) * sb.z + bf2f(e[7]) * sb.w;
                    d = half_red_sum(d);
                    if (l32 == 0) rinF[row] = d;
                }
                // s4b: positional channels
                #pragma unroll
                for (int it = 0; it < 2; it++) {
                    int row = it * 32 + hwid;
                    float d = 0.f;
                    if (row < 40) {
                        u16x8 p = *reinterpret_cast<const u16x8*>(pos2t + (size_t)row * 256 + l32 * 8);
                        d = bf2f(p[0]) * sa.x + bf2f(p[1]) * sa.y
                          + bf2f(p[2]) * sa.z + bf2f(p[3]) * sa.w
                          + bf2f(p[4]) * sb.x + bf2f(p[5]) * sb.y
                          + bf2f(p[6]) * sb.z + bf2f(p[7]) * sb.w;
                    }
                    d = half_red_sum(d);
                    if (l32 == 0 && row < 40) rinF[256 + row] = d;
                }
            }
            __syncthreads();
            // ctx-part gates (critical path, 37 iters) + combine with hacc
            if (tid < 768) {
                float c0 = 0.f, c1 = 0.f;
                #pragma unroll 4
                for (int it = 0; it < 37; it++) {
                    u16x8 w = *reinterpret_cast<const u16x8*>(WpackC + ((size_t)it * 1024 + tid) * 8);
                    float4 ra = *reinterpret_cast<const float4*>(rinF + it * 8);
                    float4 rb = *reinterpret_cast<const float4*>(rinF + it * 8 + 4);
                    c0 += bf2f(w[0]) * ra.x + bf2f(w[2]) * ra.z
                        + bf2f(w[4]) * rb.x + bf2f(w[6]) * rb.z;
                    c1 += bf2f(w[1]) * ra.y + bf2f(w[3]) * ra.w
                        + bf2f(w[5]) * rb.y + bf2f(w[7]) * rb.w;
                }
                float cacc = c0 + c1;
                if (tid < 512) rzS[tid] = cacc + hacc;
                else { inS[tid - 512] = cacc; hnS[tid - 512] = hacc; }
            }
            __syncthreads();
        }
    }
}

// ---------------- loss = 0.2 * mean_b(nll) ----------------
__global__ void k_reduce(const float* __restrict__ nll, float* __restrict__ out) {
    __shared__ float red[2];
    float v = nll[threadIdx.x];
    v = wave_red_sum(v);
    if ((threadIdx.x & 63) == 0) red[threadIdx.x >> 6] = v;
    __syncthreads();
    if (threadIdx.x == 0) out[0] = 0.2f * (red[0] + red[1]) * (1.f / 128.f);
}

extern "C" void kernel_launch(void* const* d_in, const int* in_sizes, int n_in,
                              void* d_out, int out_size, void* d_ws, size_t ws_size,
                              hipStream_t stream) {
    const float* x        = (const float*)d_in[0];
    const int*   dec_tgt  = (const int*)d_in[1];
    const int*   word_tgt = (const int*)d_in[2];
    const float* conv_w   = (const float*)d_in[3];
    const float* conv_b   = (const float*)d_in[4];
    const float* emb_dec  = (const float*)d_in[5];
    const float* word_w   = (const float*)d_in[6];
    const float* word_b   = (const float*)d_in[7];
    const float* attn_w   = (const float*)d_in[8];
    const float* attn_b   = (const float*)d_in[9];
    const float* attn_v   = (const float*)d_in[10];
    const float* gru_wih  = (const float*)d_in[11];
    const float* gru_bih  = (const float*)d_in[12];
    const float* gru_whh  = (const float*)d_in[13];
    const float* gru_bhh  = (const float*)d_in[14];
    const float* out_w    = (const float*)d_in[15];
    const float* out_b    = (const float*)d_in[16];
    const float* x_emb    = (const float*)d_in[17];
    const float* y_emb    = (const float*)d_in[18];

    char* ws = (char*)d_ws;
    size_t off = 0;
    auto alloc = [&](size_t bytes) -> void* {
        void* p = ws + off;
        off = (off + bytes + 255) & ~(size_t)255;
        return p;
    };
    unsigned short* Xt     = (unsigned short*)alloc((size_t)B * 16 * 64 * 256 * 2);  // 67MB
    unsigned short* enc_bf = (unsigned short*)alloc((size_t)B * L * CENC * 2);        // 19.4MB
    unsigned short* Wt     = (unsigned short*)alloc((size_t)9 * 256 * 256 * 2);
    float* E      = (float*)alloc((size_t)NC * HID * 4);
    unsigned short* wA_bf  = (unsigned short*)alloc((size_t)HID * HID * 2);
    unsigned short* ow_bf  = (unsigned short*)alloc((size_t)NC * HID * 2);
    unsigned short* wE_bf  = (unsigned short*)alloc((size_t)HID * 320 * 2);
    unsigned short* WpackC = (unsigned short*)alloc((size_t)37 * 1024 * 8 * 2);       // 606KB
    unsigned short* WpackH = (unsigned short*)alloc((size_t)32 * 1024 * 8 * 2);       // 524KB
    unsigned short* WgE    = (unsigned short*)alloc((size_t)256 * 768 * 2);
    float* giE    = (float*)alloc((size_t)NC * 768 * 4);
    unsigned short* pos2t  = (unsigned short*)alloc((size_t)40 * 256 * 2);
    float* nllG   = (float*)alloc((size_t)B * 4);
    u64* hX64     = (u64*)alloc((size_t)B * 256 * 8);
    u64* sX64     = (u64*)alloc((size_t)B * 256 * 8);
    // ep_t / enc_t alias Xt (dead after k_convmm)
    unsigned short* ep_t  = Xt;
    unsigned short* enc_t = Xt + (size_t)B * L * HID;
    float* out    = (float*)d_out;

    hipLaunchKernelGGL(k_upsxt, dim3(16, 128), dim3(256), 0, stream, x, Xt);
    hipLaunchKernelGGL(k_preall, dim3(4151), dim3(256), 0, stream,
                       conv_w, x_emb, y_emb, emb_dec, word_w, word_b, attn_w, out_w,
                       gru_wih, gru_whh,
                       Wt, enc_bf, pos2t, E, wA_bf, ow_bf, wE_bf, WpackC, WpackH, WgE,
                       hX64, sX64);
    hipLaunchKernelGGL(k_convmm, dim3(1024, 2), dim3(256), 0, stream, Xt, Wt, conv_b, enc_bf);
    hipLaunchKernelGGL(k_gie, dim3(163), dim3(768), 0, stream, E, WgE, gru_bih, giE);
    hipLaunchKernelGGL(k_epenct, dim3(8, 128), dim3(256), 0, stream, enc_bf, wE_bf, ep_t, enc_t);
    hipLaunchKernelGGL(k_steps, dim3(256), dim3(1024), 0, stream,
                       giE, gru_bhh, ep_t, enc_t, wA_bf, ow_bf, pos2t, WpackC, WpackH,
                       attn_b, attn_v, out_b, dec_tgt, word_tgt, nllG,
                       hX64, sX64);
    hipLaunchKernelGGL(k_reduce, dim3(1), dim3(128), 0, stream, nllG, out);
}